// Round 17
// baseline (92.262 us; speedup 1.0000x reference)
//
#include <hip/hip_runtime.h>
#include <math.h>

// No implicit contraction — every FMA below is explicit.
#pragma clang fp contract(off)

#define C_IMG   16
#define C_LIDAR 16
#define IMG_H   376
#define IMG_W   1248
#define C_OUT   (C_IMG + C_LIDAR)

__global__ __launch_bounds__(256) void voxel_img_concat_kernel(
    const float* __restrict__ vfeat,    // (N, 16)
    const int*   __restrict__ vcoord,   // (N, 4)  [b, z, y, x]
    const float* __restrict__ images,   // (B, 16, 376, 1248)
    const float* __restrict__ calib,    // (B, 3, 4)
    float*       __restrict__ out,      // (N, 32)
    int n_vox)
{
    int n = blockIdx.x * blockDim.x + threadIdx.x;
    if (n >= n_vox) return;

    int4 c4 = ((const int4*)vcoord)[n];
    int b = c4.x, z = c4.y, y = c4.z, x = c4.w;

    // Established: sep-f32 coords (double-rounded mul then add) — B-plateau.
    float px = (float)x * 0.05f;
    float py = (float)y * 0.05f + -25.6f;
    float pz = (float)z * 0.1f  + -2.0f;

    const float* P = calib + b * 12;

    // Ascending FMA dot (llvm.fmuladd chain, acc = 0) — XLA CPU dot emitter.
    float pr0 = fmaf(P[3], 1.0f, fmaf(P[2], pz, fmaf(P[1], py, fmaf(P[0], px, 0.0f))));
    float pr1 = fmaf(P[7], 1.0f, fmaf(P[6], pz, fmaf(P[5], py, fmaf(P[4], px, 0.0f))));
    float pr2 = fmaf(P[11], 1.0f, fmaf(P[10], pz, fmaf(P[9], py, fmaf(P[8], px, 0.0f))));

    // KEY CHANGE vs r15: CORRECTLY-ROUNDED reciprocal (XLA's
    // div(A, broadcast(B)) -> mul(A, broadcast(1/B)) rewrite: 1/B is a true
    // IEEE divide, then a plain RN multiply). NOT the HW v_rcp approximation.
    float inv = 1.0f / pr2;    // CR divide (hipcc default '/': r5≡r2 evidence)
    float uf = pr0 * inv;      // plain RN mul (contract off)
    float vf = pr1 * inv;

    int u = (int)uf;        // trunc toward zero == astype(int32), f32 quotient
    int v = (int)vf;

    bool valid = (u >= 0) & (u < IMG_W) & (v >= 0) & (v < IMG_H);
    int uc = min(max(u, 0), IMG_W - 1);
    int vc = min(max(v, 0), IMG_H - 1);

    const float* ib = images + (size_t)b * (C_IMG * IMG_H * IMG_W)
                             + (size_t)vc * IMG_W + uc;

    float row[C_IMG];
    #pragma unroll
    for (int c = 0; c < C_IMG; ++c) {
        float g = ib[(size_t)c * (IMG_H * IMG_W)];
        row[c] = valid ? g : 0.0f;
    }

    const float4* vfr = (const float4*)(vfeat + (size_t)n * C_LIDAR);
    float4 f0 = vfr[0], f1 = vfr[1], f2 = vfr[2], f3 = vfr[3];

    float4* ov = (float4*)(out + (size_t)n * C_OUT);
    ov[0] = make_float4(row[0],  row[1],  row[2],  row[3]);
    ov[1] = make_float4(row[4],  row[5],  row[6],  row[7]);
    ov[2] = make_float4(row[8],  row[9],  row[10], row[11]);
    ov[3] = make_float4(row[12], row[13], row[14], row[15]);
    ov[4] = f0;
    ov[5] = f1;
    ov[6] = f2;
    ov[7] = f3;
}

extern "C" void kernel_launch(void* const* d_in, const int* in_sizes, int n_in,
                              void* d_out, int out_size, void* d_ws, size_t ws_size,
                              hipStream_t stream) {
    const float* vfeat  = (const float*)d_in[0];
    const int*   vcoord = (const int*)d_in[1];
    const float* images = (const float*)d_in[2];
    const float* calib  = (const float*)d_in[3];
    float* out = (float*)d_out;

    int n_vox = in_sizes[1] / 4;   // voxel_coords is (N, 4)
    dim3 block(256);
    dim3 grid((n_vox + 255) / 256);
    voxel_img_concat_kernel<<<grid, block, 0, stream>>>(vfeat, vcoord, images, calib, out, n_vox);
}

// Round 18
// 91.394 us; speedup vs baseline: 1.0095x; 1.0095x over previous
//
#include <hip/hip_runtime.h>
#include <math.h>

// No implicit contraction — the projection arithmetic below is bit-frozen
// (verified absmax 0.0 in round 17). Do not change any rounding.
#pragma clang fp contract(off)

#define C_IMG   16
#define C_LIDAR 16
#define IMG_H   376
#define IMG_W   1248
#define HW      (IMG_H * IMG_W)
#define C_OUT   (C_IMG + C_LIDAR)

// 8 threads per voxel: lanes 0-3 project+gather 4 channels each,
// lanes 4-7 copy the 4 lidar-feature float4s. Each thread writes exactly
// one float4 of the 32-float output row -> fully coalesced stores.
__global__ __launch_bounds__(256) void voxel_img_concat_kernel(
    const float* __restrict__ vfeat,    // (N, 16)
    const int*   __restrict__ vcoord,   // (N, 4)  [b, z, y, x]
    const float* __restrict__ images,   // (B, 16, 376, 1248)
    const float* __restrict__ calib,    // (B, 3, 4)
    float*       __restrict__ out,      // (N, 32)
    int n_vox)
{
    int tid  = blockIdx.x * blockDim.x + threadIdx.x;
    int n    = tid >> 3;        // voxel index
    int lane = tid & 7;         // 0..7 within voxel
    if (n >= n_vox) return;

    float4* ov = (float4*)(out + (size_t)n * C_OUT);

    if (lane >= 4) {
        // lidar-feature copy: one float4 per lane
        const float4* vfr = (const float4*)(vfeat + (size_t)n * C_LIDAR);
        ov[lane] = vfr[lane - 4];
        return;
    }

    int4 c4 = ((const int4*)vcoord)[n];
    int b = c4.x, z = c4.y, y = c4.z, x = c4.w;

    // ---- bit-frozen projection (r17-verified) ----
    float px = (float)x * 0.05f;
    float py = (float)y * 0.05f + -25.6f;
    float pz = (float)z * 0.1f  + -2.0f;

    const float* P = calib + b * 12;
    float pr0 = fmaf(P[3], 1.0f, fmaf(P[2], pz, fmaf(P[1], py, fmaf(P[0], px, 0.0f))));
    float pr1 = fmaf(P[7], 1.0f, fmaf(P[6], pz, fmaf(P[5], py, fmaf(P[4], px, 0.0f))));
    float pr2 = fmaf(P[11], 1.0f, fmaf(P[10], pz, fmaf(P[9], py, fmaf(P[8], px, 0.0f))));

    float inv = 1.0f / pr2;    // CR reciprocal (XLA div->mul rewrite)
    float uf = pr0 * inv;      // plain RN mul
    float vf = pr1 * inv;

    int u = (int)uf;
    int v = (int)vf;
    // ---- end bit-frozen section ----

    bool valid = (u >= 0) & (u < IMG_W) & (v >= 0) & (v < IMG_H);
    int uc = min(max(u, 0), IMG_W - 1);
    int vc = min(max(v, 0), IMG_H - 1);

    const float* ib = images + (size_t)b * (C_IMG * HW)
                             + (size_t)vc * IMG_W + uc
                             + (size_t)(lane * 4) * HW;

    // 4 independent scattered loads (channels 4*lane .. 4*lane+3)
    float g0 = ib[0];
    float g1 = ib[(size_t)1 * HW];
    float g2 = ib[(size_t)2 * HW];
    float g3 = ib[(size_t)3 * HW];

    float4 r;
    r.x = valid ? g0 : 0.0f;
    r.y = valid ? g1 : 0.0f;
    r.z = valid ? g2 : 0.0f;
    r.w = valid ? g3 : 0.0f;
    ov[lane] = r;
}

extern "C" void kernel_launch(void* const* d_in, const int* in_sizes, int n_in,
                              void* d_out, int out_size, void* d_ws, size_t ws_size,
                              hipStream_t stream) {
    const float* vfeat  = (const float*)d_in[0];
    const int*   vcoord = (const int*)d_in[1];
    const float* images = (const float*)d_in[2];
    const float* calib  = (const float*)d_in[3];
    float* out = (float*)d_out;

    int n_vox = in_sizes[1] / 4;   // voxel_coords is (N, 4)
    long long total = (long long)n_vox * 8;
    dim3 block(256);
    dim3 grid((unsigned)((total + 255) / 256));
    voxel_img_concat_kernel<<<grid, block, 0, stream>>>(vfeat, vcoord, images, calib, out, n_vox);
}

// Round 19
// 90.593 us; speedup vs baseline: 1.0184x; 1.0088x over previous
//
#include <hip/hip_runtime.h>
#include <math.h>

// No implicit contraction — the projection arithmetic below is bit-frozen
// (verified absmax 0.0 in round 17). Do not change any rounding.
#pragma clang fp contract(off)

#define C_IMG   16
#define C_LIDAR 16
#define IMG_H   376
#define IMG_W   1248
#define HW      (IMG_H * IMG_W)
#define C_OUT   (C_IMG + C_LIDAR)

// Pass 1: (B,C,H,W) -> (B,H,W,C). One thread per pixel: 16 coalesced
// plane reads, one 64B contiguous write (4x float4).
__global__ __launch_bounds__(256) void transpose_kernel(
    const float* __restrict__ images,   // (B, 16, H, W)
    float*       __restrict__ ws,       // (B, H, W, 16)
    int total_pixels)                   // B * H * W
{
    int p = blockIdx.x * blockDim.x + threadIdx.x;
    if (p >= total_pixels) return;
    int b   = p / HW;
    int pix = p - b * HW;

    const float* src = images + (size_t)b * (C_IMG * HW) + pix;
    float4 o0, o1, o2, o3;
    o0.x = src[(size_t) 0 * HW]; o0.y = src[(size_t) 1 * HW];
    o0.z = src[(size_t) 2 * HW]; o0.w = src[(size_t) 3 * HW];
    o1.x = src[(size_t) 4 * HW]; o1.y = src[(size_t) 5 * HW];
    o1.z = src[(size_t) 6 * HW]; o1.w = src[(size_t) 7 * HW];
    o2.x = src[(size_t) 8 * HW]; o2.y = src[(size_t) 9 * HW];
    o2.z = src[(size_t)10 * HW]; o2.w = src[(size_t)11 * HW];
    o3.x = src[(size_t)12 * HW]; o3.y = src[(size_t)13 * HW];
    o3.z = src[(size_t)14 * HW]; o3.w = src[(size_t)15 * HW];

    float4* dst = (float4*)(ws + (size_t)p * C_IMG);
    dst[0] = o0; dst[1] = o1; dst[2] = o2; dst[3] = o3;
}

// Pass 2: 8 threads per voxel; lanes 0-3 read one float4 each of the
// SAME 64B pixel line from ws; lanes 4-7 copy vfeat. Coalesced stores.
__global__ __launch_bounds__(256) void gather_kernel(
    const float* __restrict__ vfeat,    // (N, 16)
    const int*   __restrict__ vcoord,   // (N, 4)  [b, z, y, x]
    const float* __restrict__ ws,       // (B, H, W, 16)
    const float* __restrict__ calib,    // (B, 3, 4)
    float*       __restrict__ out,      // (N, 32)
    int n_vox)
{
    int tid  = blockIdx.x * blockDim.x + threadIdx.x;
    int n    = tid >> 3;
    int lane = tid & 7;
    if (n >= n_vox) return;

    float4* ov = (float4*)(out + (size_t)n * C_OUT);

    if (lane >= 4) {
        const float4* vfr = (const float4*)(vfeat + (size_t)n * C_LIDAR);
        ov[lane] = vfr[lane - 4];
        return;
    }

    int4 c4 = ((const int4*)vcoord)[n];
    int b = c4.x, z = c4.y, y = c4.z, x = c4.w;

    // ---- bit-frozen projection (r17-verified) ----
    float px = (float)x * 0.05f;
    float py = (float)y * 0.05f + -25.6f;
    float pz = (float)z * 0.1f  + -2.0f;

    const float* P = calib + b * 12;
    float pr0 = fmaf(P[3], 1.0f, fmaf(P[2], pz, fmaf(P[1], py, fmaf(P[0], px, 0.0f))));
    float pr1 = fmaf(P[7], 1.0f, fmaf(P[6], pz, fmaf(P[5], py, fmaf(P[4], px, 0.0f))));
    float pr2 = fmaf(P[11], 1.0f, fmaf(P[10], pz, fmaf(P[9], py, fmaf(P[8], px, 0.0f))));

    float inv = 1.0f / pr2;    // CR reciprocal (XLA div->mul rewrite)
    float uf = pr0 * inv;      // plain RN mul
    float vf = pr1 * inv;

    int u = (int)uf;
    int v = (int)vf;
    // ---- end bit-frozen section ----

    bool valid = (u >= 0) & (u < IMG_W) & (v >= 0) & (v < IMG_H);
    int uc = min(max(u, 0), IMG_W - 1);
    int vc = min(max(v, 0), IMG_H - 1);

    const float4* line = (const float4*)(ws
        + ((size_t)b * HW + (size_t)vc * IMG_W + uc) * C_IMG);
    float4 g = line[lane];

    float4 r;
    r.x = valid ? g.x : 0.0f;
    r.y = valid ? g.y : 0.0f;
    r.z = valid ? g.z : 0.0f;
    r.w = valid ? g.w : 0.0f;
    ov[lane] = r;
}

// Fallback (r18 path) if workspace is too small for the transposed image.
__global__ __launch_bounds__(256) void gather_direct_kernel(
    const float* __restrict__ vfeat,
    const int*   __restrict__ vcoord,
    const float* __restrict__ images,
    const float* __restrict__ calib,
    float*       __restrict__ out,
    int n_vox)
{
    int tid  = blockIdx.x * blockDim.x + threadIdx.x;
    int n    = tid >> 3;
    int lane = tid & 7;
    if (n >= n_vox) return;

    float4* ov = (float4*)(out + (size_t)n * C_OUT);
    if (lane >= 4) {
        const float4* vfr = (const float4*)(vfeat + (size_t)n * C_LIDAR);
        ov[lane] = vfr[lane - 4];
        return;
    }

    int4 c4 = ((const int4*)vcoord)[n];
    int b = c4.x, z = c4.y, y = c4.z, x = c4.w;

    float px = (float)x * 0.05f;
    float py = (float)y * 0.05f + -25.6f;
    float pz = (float)z * 0.1f  + -2.0f;

    const float* P = calib + b * 12;
    float pr0 = fmaf(P[3], 1.0f, fmaf(P[2], pz, fmaf(P[1], py, fmaf(P[0], px, 0.0f))));
    float pr1 = fmaf(P[7], 1.0f, fmaf(P[6], pz, fmaf(P[5], py, fmaf(P[4], px, 0.0f))));
    float pr2 = fmaf(P[11], 1.0f, fmaf(P[10], pz, fmaf(P[9], py, fmaf(P[8], px, 0.0f))));

    float inv = 1.0f / pr2;
    float uf = pr0 * inv;
    float vf = pr1 * inv;
    int u = (int)uf;
    int v = (int)vf;

    bool valid = (u >= 0) & (u < IMG_W) & (v >= 0) & (v < IMG_H);
    int uc = min(max(u, 0), IMG_W - 1);
    int vc = min(max(v, 0), IMG_H - 1);

    const float* ib = images + (size_t)b * (C_IMG * HW)
                             + (size_t)vc * IMG_W + uc
                             + (size_t)(lane * 4) * HW;
    float g0 = ib[0];
    float g1 = ib[(size_t)1 * HW];
    float g2 = ib[(size_t)2 * HW];
    float g3 = ib[(size_t)3 * HW];

    float4 r;
    r.x = valid ? g0 : 0.0f;
    r.y = valid ? g1 : 0.0f;
    r.z = valid ? g2 : 0.0f;
    r.w = valid ? g3 : 0.0f;
    ov[lane] = r;
}

extern "C" void kernel_launch(void* const* d_in, const int* in_sizes, int n_in,
                              void* d_out, int out_size, void* d_ws, size_t ws_size,
                              hipStream_t stream) {
    const float* vfeat  = (const float*)d_in[0];
    const int*   vcoord = (const int*)d_in[1];
    const float* images = (const float*)d_in[2];
    const float* calib  = (const float*)d_in[3];
    float* out = (float*)d_out;

    int n_vox = in_sizes[1] / 4;            // voxel_coords is (N, 4)
    int total_pixels = in_sizes[2] / C_IMG; // B * H * W
    size_t ws_needed = (size_t)total_pixels * C_IMG * sizeof(float);

    long long total = (long long)n_vox * 8;
    dim3 block(256);
    dim3 ggrid((unsigned)((total + 255) / 256));

    if (ws_size >= ws_needed) {
        float* ws = (float*)d_ws;
        dim3 tgrid((unsigned)((total_pixels + 255) / 256));
        transpose_kernel<<<tgrid, block, 0, stream>>>(images, ws, total_pixels);
        gather_kernel<<<ggrid, block, 0, stream>>>(vfeat, vcoord, ws, calib, out, n_vox);
    } else {
        gather_direct_kernel<<<ggrid, block, 0, stream>>>(vfeat, vcoord, images, calib, out, n_vox);
    }
}